// Round 1
// baseline (59.858 us; speedup 1.0000x reference)
//
#include <hip/hip_runtime.h>

// y[b, i] = input[b, i] * weight[i, i] + bias[i]
// B=8192 rows, N=4096 cols, all fp32. Pure streaming elementwise op.
//
// Layout trick: one block of 256 threads * float4 covers exactly one row
// (256*4 = 1024... no: 256 threads * 4 floats = 1024). We need 4096 floats
// per row -> use 256 threads * 4 float4 each? Simpler: 1024 threads? Keep it
// clean: each thread owns a FIXED set of 4 columns (tid*4 .. tid*4+3) within
// a 1024-column quarter; block covers one row via 4 column-quarters handled
// by tid mapping below. To keep diag/bias register-resident we instead use
// 256 threads each owning 16 columns (4 x float4) of one row.

constexpr int N_COLS = 4096;
constexpr int B_ROWS = 8192;

__global__ __launch_bounds__(256) void diag_scale_bias(
    const float* __restrict__ in,
    const float* __restrict__ w,
    const float* __restrict__ bias,
    float* __restrict__ out)
{
    const int tid = threadIdx.x;            // 0..255
    // Each thread owns 4 float4 chunks: columns tid*4 + q*1024, q=0..3.
    // That covers 256*4*4 = 4096 columns = one full row.
    float4 d[4], bv[4];
    #pragma unroll
    for (int q = 0; q < 4; ++q) {
        const int c = tid * 4 + q * 1024;
        // diagonal of W: w[c*(N+1)] — one element per cache line, L2-resident
        // after first touch (4096 distinct lines total across the grid).
        d[q].x = w[(size_t)(c + 0) * (N_COLS + 1)];
        d[q].y = w[(size_t)(c + 1) * (N_COLS + 1)];
        d[q].z = w[(size_t)(c + 2) * (N_COLS + 1)];
        d[q].w = w[(size_t)(c + 3) * (N_COLS + 1)];
        bv[q]  = *reinterpret_cast<const float4*>(bias + c);
    }

    // Grid-stride over rows; diag+bias stay in registers.
    for (int row = blockIdx.x; row < B_ROWS; row += gridDim.x) {
        const size_t base = (size_t)row * N_COLS;
        #pragma unroll
        for (int q = 0; q < 4; ++q) {
            const int c = tid * 4 + q * 1024;
            const float4 iv = *reinterpret_cast<const float4*>(in + base + c);
            float4 ov;
            ov.x = iv.x * d[q].x + bv[q].x;
            ov.y = iv.y * d[q].y + bv[q].y;
            ov.z = iv.z * d[q].z + bv[q].z;
            ov.w = iv.w * d[q].w + bv[q].w;
            *reinterpret_cast<float4*>(out + base + c) = ov;
        }
    }
}

extern "C" void kernel_launch(void* const* d_in, const int* in_sizes, int n_in,
                              void* d_out, int out_size, void* d_ws, size_t ws_size,
                              hipStream_t stream) {
    const float* in   = (const float*)d_in[0];   // [8192, 4096]
    const float* w    = (const float*)d_in[1];   // [4096, 4096]
    const float* bias = (const float*)d_in[2];   // [4096]
    float* out        = (float*)d_out;           // [8192, 4096]

    // 2048 blocks * 256 threads: 8 blocks/CU on 256 CUs, 32 waves/CU.
    // Each block processes 4 rows via grid-stride.
    diag_scale_bias<<<2048, 256, 0, stream>>>(in, w, bias, out);
}

// Round 3
// 44.797 us; speedup vs baseline: 1.3362x; 1.3362x over previous
//
#include <hip/hip_runtime.h>

// y[b, i] = input[b, i] * weight[i, i] + bias[i]
// B=8192 rows, N=4096 cols, fp32. Pure streaming, memory-bound.
//
// Decomposition: grid = COL_GROUPS x ROW_GROUPS.
//   - colGroup: 1024 columns (256 threads x float4) -> each thread owns a
//     FIXED 4-column slice; diag + bias live in 8 registers, loaded once.
//   - rowGroup: 16 consecutive rows streamed per block.
// Stores are non-temporal (global_store_dwordx4 ... nt): output is
// write-once; bypassing L2/L3 keeps the input stream resident in Infinity
// Cache across graph replays.

constexpr int N_COLS = 4096;
constexpr int B_ROWS = 8192;
constexpr int COL_GROUPS = 4;                       // 1024 cols each
constexpr int ROW_GROUPS = 512;                     // 16 rows each
constexpr int ROWS_PER_BLOCK = B_ROWS / ROW_GROUPS; // 16

// Native clang vector type — required by __builtin_nontemporal_store
// (HIP's float4 is a struct and is rejected).
typedef float fx4 __attribute__((ext_vector_type(4)));

__global__ __launch_bounds__(256) void diag_scale_bias(
    const float* __restrict__ in,
    const float* __restrict__ w,
    const float* __restrict__ bias,
    float* __restrict__ out)
{
    const int tid = threadIdx.x;                 // 0..255
    const int cg  = blockIdx.x % COL_GROUPS;
    const int rg  = blockIdx.x / COL_GROUPS;
    const int c   = cg * 1024 + tid * 4;         // this thread's 4 columns

    // diag(W): w[c*(N+1)] — 4 scalar loads, one line each; 4096 distinct
    // lines chip-wide, L2/L3-resident after first touch.
    fx4 d;
    d.x = w[(size_t)(c + 0) * (N_COLS + 1)];
    d.y = w[(size_t)(c + 1) * (N_COLS + 1)];
    d.z = w[(size_t)(c + 2) * (N_COLS + 1)];
    d.w = w[(size_t)(c + 3) * (N_COLS + 1)];
    const fx4 bv = *reinterpret_cast<const fx4*>(bias + c);

    const int row0 = rg * ROWS_PER_BLOCK;
    #pragma unroll 4
    for (int r = 0; r < ROWS_PER_BLOCK; ++r) {
        const size_t idx = (size_t)(row0 + r) * N_COLS + c;
        const fx4 iv = *reinterpret_cast<const fx4*>(in + idx);
        fx4 ov;
        ov.x = fmaf(iv.x, d.x, bv.x);
        ov.y = fmaf(iv.y, d.y, bv.y);
        ov.z = fmaf(iv.z, d.z, bv.z);
        ov.w = fmaf(iv.w, d.w, bv.w);
        __builtin_nontemporal_store(ov, reinterpret_cast<fx4*>(out + idx));
    }
}

extern "C" void kernel_launch(void* const* d_in, const int* in_sizes, int n_in,
                              void* d_out, int out_size, void* d_ws, size_t ws_size,
                              hipStream_t stream) {
    const float* in   = (const float*)d_in[0];   // [8192, 4096]
    const float* w    = (const float*)d_in[1];   // [4096, 4096]
    const float* bias = (const float*)d_in[2];   // [4096]
    float* out        = (float*)d_out;           // [8192, 4096]

    // 4 col-groups x 512 row-groups = 2048 blocks, 256 threads each:
    // 8 blocks/CU, full 32-wave occupancy. Each block streams 16 rows.
    diag_scale_bias<<<COL_GROUPS * ROW_GROUPS, 256, 0, stream>>>(in, w, bias, out);
}